// Round 7
// baseline (104.073 us; speedup 1.0000x reference)
//
#include <hip/hip_runtime.h>

#define NB 16384
#define TT 10
#define DIN 256
#define HH 16
#define NG 64      // 4*H
#define NF 160     // T*H

typedef __attribute__((ext_vector_type(8))) _Float16 half8;
typedef __attribute__((ext_vector_type(4))) float f32x4;
typedef unsigned int u32;

__device__ __forceinline__ float rl_(float v, int l) {
    return __int_as_float(__builtin_amdgcn_readlane(__float_as_int(v), l));
}

// fire-and-forget 16B/lane global->LDS (lds dest: wave-uniform base + lane*16)
__device__ __forceinline__ void gld16(const float* g, float* l) {
    __builtin_amdgcn_global_load_lds(
        (const __attribute__((address_space(1))) u32*)g,
        (__attribute__((address_space(3))) u32*)l, 16, 0, 0);
}

// K0: one-time prep. B fragments (fp16, lane order) + fused layer-0 bias.
// lane l holds B[col=c*16+(l&15)][k=s*32+(l>>4)*8+j], at Bf[(c*8+s)*64+l].
__global__ __launch_bounds__(256) void k_prep(
        const float* __restrict__ w, const float* __restrict__ bi,
        const float* __restrict__ bh, half8* __restrict__ Bf,
        float* __restrict__ bsum) {
    const int fi = blockIdx.x * 256 + threadIdx.x;   // 0..2047
    const int c = fi >> 9;
    const int s = (fi >> 6) & 7;
    const int ll = fi & 63;
    const int row = c * 16 + (ll & 15);
    const int k0 = s * 32 + ((ll >> 4) << 3);
    const float* wp = w + (size_t)row * DIN + k0;
    float4 a = *(const float4*)wp;
    float4 b = *(const float4*)(wp + 4);
    half8 h;
    h[0] = (_Float16)a.x; h[1] = (_Float16)a.y;
    h[2] = (_Float16)a.z; h[3] = (_Float16)a.w;
    h[4] = (_Float16)b.x; h[5] = (_Float16)b.y;
    h[6] = (_Float16)b.z; h[7] = (_Float16)b.w;
    Bf[fi] = h;
    if (blockIdx.x == 0 && threadIdx.x < NG)
        bsum[threadIdx.x] = bi[threadIdx.x] + bh[threadIdx.x];
}

// K1: xg = x.w^T + bias via f16 MFMA (hi/lo split).
// global_load_lds staging: each wave owns 16 rows; K=256 in 4 chunks of 64
// (4KB, double-buffered). Source-side XOR swizzle (cb ^= (row&7)<<4) gives
// even bank spread on the strided ds_read_b128. Counted vmcnt (never 0 until
// the last chunk), no barriers in the K-loop (waves consume only their own
// staged rows; only Bl needs the single startup barrier).
__global__ __launch_bounds__(256) void k_proj(
        const float* __restrict__ x, const half8* __restrict__ Bf,
        const float* __restrict__ bsum, float* __restrict__ xgF) {
    __shared__ half8 Bl[2048];          // 32 KB, shared B fragments
    __shared__ float xs[4][2][1024];    // 4 waves x 2 bufs x 4 KB
    const int tid = threadIdx.x;
    const int l = tid & 63;
    const int wv = tid >> 6;

    // stage Bl via global_load_lds (linear, 8 issues per wave), one barrier
    #pragma unroll
    for (int q = 0; q < 8; ++q)
        gld16((const float*)(Bf + (wv * 8 + q) * 64 + l),
              (float*)(Bl + (wv * 8 + q) * 64));
    __syncthreads();   // drains the Bl issues; Bl visible to all waves

    const int wid = (blockIdx.x * 256 + tid) >> 6;   // global wave id
    const int row0 = wid * 16;
    float* xbuf = &xs[wv][0][0];

    // stage chunk kc (64 K-floats) into buf kc&1: 4 pieces of 4 rows x 256B
    auto stage = [&](int kc) {
        #pragma unroll
        for (int p = 0; p < 4; ++p) {
            const int r = p * 4 + (l >> 4);                      // row in tile
            const int cb = (kc << 8) + ((((l & 15) << 4)) ^ ((r & 7) << 4));
            gld16(x + (size_t)(row0 + r) * DIN + (cb >> 2),
                  xbuf + (kc & 1) * 1024 + p * 256);
        }
    };

    f32x4 acc[4];
    #pragma unroll
    for (int c = 0; c < 4; ++c) acc[c] = (f32x4)0.0f;

    auto compute = [&](int kc) {
        const char* bp = (const char*)(xbuf + (kc & 1) * 1024);
        const int r = l & 15;
        const int swz = (r & 7) << 4;
        const char* rowp = bp + r * 256;
        #pragma unroll
        for (int sl = 0; sl < 2; ++sl) {
            const int s = kc * 2 + sl;
            const int cb0 = sl * 128 + ((l >> 4) << 5);
            f32x4 va = *(const f32x4*)(rowp + (cb0 ^ swz));
            f32x4 vb = *(const f32x4*)(rowp + ((cb0 + 16) ^ swz));
            float fv[8] = {va.x, va.y, va.z, va.w, vb.x, vb.y, vb.z, vb.w};
            half8 ah, al;
            #pragma unroll
            for (int j = 0; j < 8; ++j) {
                _Float16 hi = (_Float16)fv[j];
                ah[j] = hi;
                al[j] = (_Float16)(fv[j] - (float)hi);
            }
            #pragma unroll
            for (int c = 0; c < 4; ++c) {
                half8 bf = Bl[(c * 8 + s) * 64 + l];
                acc[c] = __builtin_amdgcn_mfma_f32_16x16x32_f16(ah, bf, acc[c], 0, 0, 0);
                acc[c] = __builtin_amdgcn_mfma_f32_16x16x32_f16(al, bf, acc[c], 0, 0, 0);
            }
        }
    };

    stage(0); stage(1);
    asm volatile("s_waitcnt vmcnt(4)" ::: "memory");   // chunk0 ready
    __builtin_amdgcn_sched_barrier(0);
    compute(0);
    stage(2);                                          // buf0 free now
    asm volatile("s_waitcnt vmcnt(4)" ::: "memory");   // chunk1 ready
    __builtin_amdgcn_sched_barrier(0);
    compute(1);
    stage(3);
    asm volatile("s_waitcnt vmcnt(4)" ::: "memory");   // chunk2 ready
    __builtin_amdgcn_sched_barrier(0);
    compute(2);
    asm volatile("s_waitcnt vmcnt(0)" ::: "memory");   // chunk3 ready
    __builtin_amdgcn_sched_barrier(0);
    compute(3);

    // epilogue: bias + coalesced fragment-layout store (16B/lane)
    #pragma unroll
    for (int c = 0; c < 4; ++c) {
        const float bb = bsum[c * 16 + (l & 15)];
        f32x4 v = acc[c];
        v.x += bb; v.y += bb; v.z += bb; v.w += bb;
        *(f32x4*)(xgF + (size_t)wid * 1024 + c * 256 + l * 4) = v;
    }
}

// K2: fused 2-layer LSTM recurrence (fragment-layout xg, full prefetch,
// readlane broadcasts, unified sig/tanh activation).
__global__ __launch_bounds__(256) void k_lstm(
        const float* __restrict__ xgF, const float* __restrict__ whh0,
        const float* __restrict__ wih1, const float* __restrict__ whh1,
        const float* __restrict__ bi1, const float* __restrict__ bh1,
        float* __restrict__ flat) {
    const int g = threadIdx.x & 63;
    const int b = blockIdx.x * 4 + (threadIdx.x >> 6);

    float xv[TT];
    #pragma unroll
    for (int t = 0; t < TT; ++t) {
        const int row = b * TT + t;
        const int addr = ((row >> 4) << 10) + ((g >> 4) << 8) +
                         (((row >> 2) & 3) << 6) + ((g & 15) << 2) + (row & 3);
        xv[t] = xgF[addr];
    }

    float w0[16], w1[16], w2[16];
    #pragma unroll
    for (int q = 0; q < 4; ++q) {
        float4 v0 = *(const float4*)(whh0 + g * HH + q * 4);
        w0[q*4+0] = v0.x; w0[q*4+1] = v0.y; w0[q*4+2] = v0.z; w0[q*4+3] = v0.w;
        float4 v1 = *(const float4*)(wih1 + g * HH + q * 4);
        w1[q*4+0] = v1.x; w1[q*4+1] = v1.y; w1[q*4+2] = v1.z; w1[q*4+3] = v1.w;
        float4 v2 = *(const float4*)(whh1 + g * HH + q * 4);
        w2[q*4+0] = v2.x; w2[q*4+1] = v2.y; w2[q*4+2] = v2.z; w2[q*4+3] = v2.w;
    }
    const float bias1 = bi1[g] + bh1[g];
    const bool isg = (g & 48) == 32;
    const float m1 = isg ? 2.0f : 1.0f;
    const float b2 = isg ? -1.0f : 0.0f;
    float h0 = 0.0f, c0 = 0.0f, h1 = 0.0f, c1 = 0.0f;

    #pragma unroll
    for (int t = 0; t < TT; ++t) {
        float s0 = xv[t], s1 = 0.0f, s2 = 0.0f, s3 = 0.0f;
        #pragma unroll
        for (int q = 0; q < 4; ++q) {
            s0 += rl_(h0, 4*q + 0) * w0[4*q + 0];
            s1 += rl_(h0, 4*q + 1) * w0[4*q + 1];
            s2 += rl_(h0, 4*q + 2) * w0[4*q + 2];
            s3 += rl_(h0, 4*q + 3) * w0[4*q + 3];
        }
        float z = ((s0 + s1) + (s2 + s3)) * m1;
        float a = m1 / (1.0f + __expf(-z)) + b2;
        float af = __shfl_down(a, 16, 64);
        float ac = __shfl_down(a, 32, 64);
        float ao = __shfl_down(a, 48, 64);
        c0 = af * c0 + a * ac;
        float e0 = __expf(2.0f * c0);
        h0 = ao * (1.0f - 2.0f / (e0 + 1.0f));

        float u0 = bias1, u1 = 0.0f, u2 = 0.0f, u3 = 0.0f;
        float v0 = 0.0f, v1 = 0.0f, v2 = 0.0f, v3 = 0.0f;
        #pragma unroll
        for (int q = 0; q < 4; ++q) {
            u0 += rl_(h0, 4*q + 0) * w1[4*q + 0];
            u1 += rl_(h0, 4*q + 1) * w1[4*q + 1];
            u2 += rl_(h0, 4*q + 2) * w1[4*q + 2];
            u3 += rl_(h0, 4*q + 3) * w1[4*q + 3];
            v0 += rl_(h1, 4*q + 0) * w2[4*q + 0];
            v1 += rl_(h1, 4*q + 1) * w2[4*q + 1];
            v2 += rl_(h1, 4*q + 2) * w2[4*q + 2];
            v3 += rl_(h1, 4*q + 3) * w2[4*q + 3];
        }
        float z1 = (((u0 + v0) + (u1 + v1)) + ((u2 + v2) + (u3 + v3))) * m1;
        float a1 = m1 / (1.0f + __expf(-z1)) + b2;
        af = __shfl_down(a1, 16, 64);
        ac = __shfl_down(a1, 32, 64);
        ao = __shfl_down(a1, 48, 64);
        c1 = af * c1 + a1 * ac;
        float e1 = __expf(2.0f * c1);
        h1 = ao * (1.0f - 2.0f / (e1 + 1.0f));

        if (g < HH) flat[(size_t)b * NF + t * HH + g] = h1;
    }
}

// K3a: per-chunk partial sums for BN stats, coalesced reads.
__global__ __launch_bounds__(192) void k_bnA(
        const float* __restrict__ flat, float* __restrict__ psum,
        float* __restrict__ psq) {
    const int f = threadIdx.x;
    if (f >= NF) return;
    const int p = blockIdx.x;
    const float* base = flat + (size_t)p * 64 * NF + f;
    float s0 = 0.0f, s1 = 0.0f, q0 = 0.0f, q1 = 0.0f;
    #pragma unroll 4
    for (int r = 0; r < 64; r += 2) {
        float a = base[(size_t)r * NF];
        float b2 = base[(size_t)(r + 1) * NF];
        s0 += a; q0 += a * a;
        s1 += b2; q1 += b2 * b2;
    }
    psum[p * NF + f] = s0 + s1;
    psq[p * NF + f] = q0 + q1;
}

// K3b: reduce partials -> fused scale/shift.
__global__ __launch_bounds__(256) void k_bnB(
        const float* __restrict__ psum, const float* __restrict__ psq,
        const float* __restrict__ gamma, const float* __restrict__ beta,
        float* __restrict__ scale, float* __restrict__ shift) {
    const int f = blockIdx.x;
    const int p = threadIdx.x;
    float s = psum[p * NF + f];
    float q = psq[p * NF + f];
    #pragma unroll
    for (int o = 32; o > 0; o >>= 1) {
        s += __shfl_down(s, o, 64);
        q += __shfl_down(q, o, 64);
    }
    __shared__ float rs[4], rq[4];
    const int wv = p >> 6;
    if ((p & 63) == 0) { rs[wv] = s; rq[wv] = q; }
    __syncthreads();
    if (p == 0) {
        float S = rs[0] + rs[1] + rs[2] + rs[3];
        float Q = rq[0] + rq[1] + rq[2] + rq[3];
        float mean = S * (1.0f / NB);
        float var = Q * (1.0f / NB) - mean * mean;
        float sc = gamma[f] * rsqrtf(var + 1e-5f);
        scale[f] = sc;
        shift[f] = beta[f] - mean * sc;
    }
}

// K4: BN-apply + LeakyReLU + concat + FC(162->2) + softmax.
__global__ __launch_bounds__(256) void k_fc(
        const float* __restrict__ flat, const float* __restrict__ scale,
        const float* __restrict__ shift, const float* __restrict__ ag,
        const float* __restrict__ fcw, const float* __restrict__ fcb,
        float* __restrict__ out) {
    const int lane = threadIdx.x & 63;
    const int b = blockIdx.x * 4 + (threadIdx.x >> 6);
    const float* fr = flat + (size_t)b * NF;
    float p0 = 0.0f, p1 = 0.0f;
    for (int f = lane; f < NF; f += 64) {
        float xn = fr[f] * scale[f] + shift[f];
        float a = xn >= 0.0f ? xn : 0.01f * xn;
        p0 += a * fcw[f];
        p1 += a * fcw[162 + f];
    }
    #pragma unroll
    for (int o = 32; o > 0; o >>= 1) {
        p0 += __shfl_down(p0, o, 64);
        p1 += __shfl_down(p1, o, 64);
    }
    if (lane == 0) {
        float a0 = ag[(size_t)b * 2 + 0], a1 = ag[(size_t)b * 2 + 1];
        float l0 = p0 + a0 * fcw[160] + a1 * fcw[161] + fcb[0];
        float l1 = p1 + a0 * fcw[162 + 160] + a1 * fcw[162 + 161] + fcb[1];
        float m = fmaxf(l0, l1);
        float e0 = __expf(l0 - m), e1 = __expf(l1 - m);
        float inv = 1.0f / (e0 + e1);
        out[(size_t)b * 2 + 0] = e0 * inv;
        out[(size_t)b * 2 + 1] = e1 * inv;
    }
}

extern "C" void kernel_launch(void* const* d_in, const int* in_sizes, int n_in,
                              void* d_out, int out_size, void* d_ws, size_t ws_size,
                              hipStream_t stream) {
    const float* x     = (const float*)d_in[0];
    const float* ag    = (const float*)d_in[1];
    const float* wih0  = (const float*)d_in[2];
    const float* whh0  = (const float*)d_in[3];
    const float* bih0  = (const float*)d_in[4];
    const float* bhh0  = (const float*)d_in[5];
    const float* wih1  = (const float*)d_in[6];
    const float* whh1  = (const float*)d_in[7];
    const float* bih1  = (const float*)d_in[8];
    const float* bhh1  = (const float*)d_in[9];
    const float* gamma = (const float*)d_in[10];
    const float* beta  = (const float*)d_in[11];
    const float* fcw   = (const float*)d_in[12];
    const float* fcb   = (const float*)d_in[13];
    float* out = (float*)d_out;

    float* ws = (float*)d_ws;
    float* xgF   = ws;                       // 10,485,760 floats (frag layout)
    float* flat  = ws + 10485760;            //  2,621,440 floats
    float* psum  = ws + 13107200;            //     40,960 floats (256*160)
    float* psq   = ws + 13148160;            //     40,960 floats
    float* scale = ws + 13189120;            //        160
    float* shift = ws + 13189280;            //        160
    half8* Bf    = (half8*)(ws + 13189440);  //      8,192 floats (32 KB)
    float* bsum  = ws + 13197632;            //         64

    k_prep<<<dim3(8),    dim3(256), 0, stream>>>(wih0, bih0, bhh0, Bf, bsum);
    k_proj<<<dim3(2560), dim3(256), 0, stream>>>(x, Bf, bsum, xgF);
    k_lstm<<<dim3(4096), dim3(256), 0, stream>>>(xgF, whh0, wih1, whh1, bih1, bhh1, flat);
    k_bnA<<<dim3(256),  dim3(192), 0, stream>>>(flat, psum, psq);
    k_bnB<<<dim3(160),  dim3(256), 0, stream>>>(psum, psq, gamma, beta, scale, shift);
    k_fc<<<dim3(4096),  dim3(256), 0, stream>>>(flat, scale, shift, ag, fcw, fcb, out);
}

// Round 9
// 102.566 us; speedup vs baseline: 1.0147x; 1.0147x over previous
//
#include <hip/hip_runtime.h>

#define NB 16384
#define TT 10
#define DIN 256
#define HH 16
#define NG 64      // 4*H
#define NF 160     // T*H

typedef __attribute__((ext_vector_type(8))) _Float16 half8;
typedef __attribute__((ext_vector_type(4))) _Float16 half4;
typedef __attribute__((ext_vector_type(4))) float f32x4;
typedef unsigned int u32;

__device__ __forceinline__ float rl_(float v, int l) {
    return __int_as_float(__builtin_amdgcn_readlane(__float_as_int(v), l));
}

// fire-and-forget 16B/lane global->LDS (lds dest: wave-uniform base + lane*16)
__device__ __forceinline__ void gld16(const float* g, float* l) {
    __builtin_amdgcn_global_load_lds(
        (const __attribute__((address_space(1))) u32*)g,
        (__attribute__((address_space(3))) u32*)l, 16, 0, 0);
}

// K0: one-time prep. B fragments (fp16, lane order) + fused layer-0 bias.
// lane l holds B[col=c*16+(l&15)][k=s*32+(l>>4)*8+j], at Bf[(c*8+s)*64+l].
__global__ __launch_bounds__(256) void k_prep(
        const float* __restrict__ w, const float* __restrict__ bi,
        const float* __restrict__ bh, half8* __restrict__ Bf,
        float* __restrict__ bsum) {
    const int fi = blockIdx.x * 256 + threadIdx.x;   // 0..2047
    const int c = fi >> 9;
    const int s = (fi >> 6) & 7;
    const int ll = fi & 63;
    const int row = c * 16 + (ll & 15);
    const int k0 = s * 32 + ((ll >> 4) << 3);
    const float* wp = w + (size_t)row * DIN + k0;
    float4 a = *(const float4*)wp;
    float4 b = *(const float4*)(wp + 4);
    half8 h;
    h[0] = (_Float16)a.x; h[1] = (_Float16)a.y;
    h[2] = (_Float16)a.z; h[3] = (_Float16)a.w;
    h[4] = (_Float16)b.x; h[5] = (_Float16)b.y;
    h[6] = (_Float16)b.z; h[7] = (_Float16)b.w;
    Bf[fi] = h;
    if (blockIdx.x == 0 && threadIdx.x < NG)
        bsum[threadIdx.x] = bi[threadIdx.x] + bh[threadIdx.x];
}

// K1: xg = x.w^T + bias via f16 MFMA (hi/lo split). R6 schedule (2-buffer,
// counted vmcnt) + RACE FIX: lgkmcnt(0)+sched_barrier fences before any
// stage() that reuses a buffer, so the scheduler cannot hoist the
// global_load_lds LDS-write above the prior chunk's ds_reads.
// Output xg stored as f16 in C-fragment layout:
//   addr = wid*1024 + c*256 + l*4 + r  (row=wid*16+(l>>4)*4+r, col=c*16+(l&15))
__global__ __launch_bounds__(256) void k_proj(
        const float* __restrict__ x, const half8* __restrict__ Bf,
        const float* __restrict__ bsum, _Float16* __restrict__ xgH) {
    __shared__ half8 Bl[2048];          // 32 KB, shared B fragments
    __shared__ float xs[4][2][1024];    // 4 waves x 2 bufs x 4 KB
    const int tid = threadIdx.x;
    const int l = tid & 63;
    const int wv = tid >> 6;

    // stage Bl via global_load_lds (linear), one startup barrier
    #pragma unroll
    for (int q = 0; q < 8; ++q)
        gld16((const float*)(Bf + (wv * 8 + q) * 64 + l),
              (float*)(Bl + (wv * 8 + q) * 64));
    __syncthreads();   // drains Bl issues; Bl visible to all waves

    const int wid = (blockIdx.x * 256 + tid) >> 6;   // global wave id
    const int row0 = wid * 16;
    float* xbuf = &xs[wv][0][0];

    // stage chunk kc (64 K-floats x 16 rows = 4KB) into buf kc&1
    auto stage = [&](int kc) {
        #pragma unroll
        for (int p = 0; p < 4; ++p) {
            const int r = p * 4 + (l >> 4);                      // row in tile
            const int cb = (kc << 8) + ((((l & 15) << 4)) ^ ((r & 7) << 4));
            gld16(x + (size_t)(row0 + r) * DIN + (cb >> 2),
                  xbuf + (kc & 1) * 1024 + p * 256);
        }
    };

    f32x4 acc[4];
    #pragma unroll
    for (int c = 0; c < 4; ++c) acc[c] = (f32x4)0.0f;

    auto compute = [&](int kc) {
        const char* bp = (const char*)(xbuf + (kc & 1) * 1024);
        const int r = l & 15;
        const int swz = (r & 7) << 4;
        const char* rowp = bp + r * 256;
        #pragma unroll
        for (int sl = 0; sl < 2; ++sl) {
            const int s = kc * 2 + sl;
            const int cb0 = sl * 128 + ((l >> 4) << 5);
            f32x4 va = *(const f32x4*)(rowp + (cb0 ^ swz));
            f32x4 vb = *(const f32x4*)(rowp + ((cb0 + 16) ^ swz));
            float fv[8] = {va.x, va.y, va.z, va.w, vb.x, vb.y, vb.z, vb.w};
            half8 ah, al;
            #pragma unroll
            for (int j = 0; j < 8; ++j) {
                _Float16 hi = (_Float16)fv[j];
                ah[j] = hi;
                al[j] = (_Float16)(fv[j] - (float)hi);
            }
            #pragma unroll
            for (int c = 0; c < 4; ++c) {
                half8 bf = Bl[(c * 8 + s) * 64 + l];
                acc[c] = __builtin_amdgcn_mfma_f32_16x16x32_f16(ah, bf, acc[c], 0, 0, 0);
                acc[c] = __builtin_amdgcn_mfma_f32_16x16x32_f16(al, bf, acc[c], 0, 0, 0);
            }
        }
    };

    stage(0); stage(1);
    asm volatile("s_waitcnt vmcnt(4)" ::: "memory");   // chunk0 ready
    __builtin_amdgcn_sched_barrier(0);
    compute(0);
    asm volatile("s_waitcnt lgkmcnt(0)" ::: "memory"); // buf0 ds_reads complete
    __builtin_amdgcn_sched_barrier(0);
    stage(2);                                          // safe to overwrite buf0
    asm volatile("s_waitcnt vmcnt(4)" ::: "memory");   // chunk1 ready
    __builtin_amdgcn_sched_barrier(0);
    compute(1);
    asm volatile("s_waitcnt lgkmcnt(0)" ::: "memory"); // buf1 ds_reads complete
    __builtin_amdgcn_sched_barrier(0);
    stage(3);
    asm volatile("s_waitcnt vmcnt(4)" ::: "memory");   // chunk2 ready
    __builtin_amdgcn_sched_barrier(0);
    compute(2);
    asm volatile("s_waitcnt vmcnt(0)" ::: "memory");   // chunk3 ready
    __builtin_amdgcn_sched_barrier(0);
    compute(3);

    // epilogue: bias + f16 pack + coalesced fragment-layout store (8B/lane)
    #pragma unroll
    for (int c = 0; c < 4; ++c) {
        const float bb = bsum[c * 16 + (l & 15)];
        half4 hv;
        hv[0] = (_Float16)(acc[c][0] + bb);
        hv[1] = (_Float16)(acc[c][1] + bb);
        hv[2] = (_Float16)(acc[c][2] + bb);
        hv[3] = (_Float16)(acc[c][3] + bb);
        *(half4*)(xgH + (size_t)wid * 1024 + c * 256 + l * 4) = hv;
    }
}

// K2: fused 2-layer LSTM recurrence + per-block BN partial sums.
// xg read (f16) from fragment layout, all 10 timesteps prefetched up front.
__global__ __launch_bounds__(256) void k_lstm(
        const _Float16* __restrict__ xgH, const float* __restrict__ whh0,
        const float* __restrict__ wih1, const float* __restrict__ whh1,
        const float* __restrict__ bi1, const float* __restrict__ bh1,
        _Float16* __restrict__ flatH, float* __restrict__ psumT,
        float* __restrict__ psqT) {
    __shared__ float ls[4][NF];   // per-wave h1 history for BN partials
    const int g = threadIdx.x & 63;
    const int wv = threadIdx.x >> 6;
    const int b = blockIdx.x * 4 + wv;

    float xv[TT];
    #pragma unroll
    for (int t = 0; t < TT; ++t) {
        const int row = b * TT + t;
        const int addr = ((row >> 4) << 10) + ((g >> 4) << 8) +
                         (((row >> 2) & 3) << 6) + ((g & 15) << 2) + (row & 3);
        xv[t] = (float)xgH[addr];
    }

    float w0[16], w1[16], w2[16];
    #pragma unroll
    for (int q = 0; q < 4; ++q) {
        float4 v0 = *(const float4*)(whh0 + g * HH + q * 4);
        w0[q*4+0] = v0.x; w0[q*4+1] = v0.y; w0[q*4+2] = v0.z; w0[q*4+3] = v0.w;
        float4 v1 = *(const float4*)(wih1 + g * HH + q * 4);
        w1[q*4+0] = v1.x; w1[q*4+1] = v1.y; w1[q*4+2] = v1.z; w1[q*4+3] = v1.w;
        float4 v2 = *(const float4*)(whh1 + g * HH + q * 4);
        w2[q*4+0] = v2.x; w2[q*4+1] = v2.y; w2[q*4+2] = v2.z; w2[q*4+3] = v2.w;
    }
    const float bias1 = bi1[g] + bh1[g];
    const bool isg = (g & 48) == 32;
    const float m1 = isg ? 2.0f : 1.0f;   // unified sig/tanh
    const float b2 = isg ? -1.0f : 0.0f;
    float h0 = 0.0f, c0 = 0.0f, h1 = 0.0f, c1 = 0.0f;

    #pragma unroll
    for (int t = 0; t < TT; ++t) {
        float s0 = xv[t], s1 = 0.0f, s2 = 0.0f, s3 = 0.0f;
        #pragma unroll
        for (int q = 0; q < 4; ++q) {
            s0 += rl_(h0, 4*q + 0) * w0[4*q + 0];
            s1 += rl_(h0, 4*q + 1) * w0[4*q + 1];
            s2 += rl_(h0, 4*q + 2) * w0[4*q + 2];
            s3 += rl_(h0, 4*q + 3) * w0[4*q + 3];
        }
        float z = ((s0 + s1) + (s2 + s3)) * m1;
        float a = m1 / (1.0f + __expf(-z)) + b2;
        float af = __shfl_down(a, 16, 64);
        float ac = __shfl_down(a, 32, 64);
        float ao = __shfl_down(a, 48, 64);
        c0 = af * c0 + a * ac;
        float e0 = __expf(2.0f * c0);
        h0 = ao * (1.0f - 2.0f / (e0 + 1.0f));

        float u0 = bias1, u1 = 0.0f, u2 = 0.0f, u3 = 0.0f;
        float v0 = 0.0f, v1 = 0.0f, v2 = 0.0f, v3 = 0.0f;
        #pragma unroll
        for (int q = 0; q < 4; ++q) {
            u0 += rl_(h0, 4*q + 0) * w1[4*q + 0];
            u1 += rl_(h0, 4*q + 1) * w1[4*q + 1];
            u2 += rl_(h0, 4*q + 2) * w1[4*q + 2];
            u3 += rl_(h0, 4*q + 3) * w1[4*q + 3];
            v0 += rl_(h1, 4*q + 0) * w2[4*q + 0];
            v1 += rl_(h1, 4*q + 1) * w2[4*q + 1];
            v2 += rl_(h1, 4*q + 2) * w2[4*q + 2];
            v3 += rl_(h1, 4*q + 3) * w2[4*q + 3];
        }
        float z1 = (((u0 + v0) + (u1 + v1)) + ((u2 + v2) + (u3 + v3))) * m1;
        float a1 = m1 / (1.0f + __expf(-z1)) + b2;
        af = __shfl_down(a1, 16, 64);
        ac = __shfl_down(a1, 32, 64);
        ao = __shfl_down(a1, 48, 64);
        c1 = af * c1 + a1 * ac;
        float e1 = __expf(2.0f * c1);
        h1 = ao * (1.0f - 2.0f / (e1 + 1.0f));

        if (g < HH) {
            flatH[(size_t)b * NF + t * HH + g] = (_Float16)h1;
            ls[wv][t * HH + g] = h1;
        }
    }

    // BN partials: reduce the block's 4 samples; transposed [f][4096] layout
    // so k_bnB reads coalesced (writes here are L2-merged).
    __syncthreads();
    const int tid = threadIdx.x;
    if (tid < NF) {
        float a0 = ls[0][tid], a1 = ls[1][tid], a2 = ls[2][tid], a3 = ls[3][tid];
        psumT[(size_t)tid * 4096 + blockIdx.x] = (a0 + a1) + (a2 + a3);
        psqT[(size_t)tid * 4096 + blockIdx.x] =
            (a0 * a0 + a1 * a1) + (a2 * a2 + a3 * a3);
    }
}

// K3: reduce 4096 block-partials per feature -> fused BN scale/shift.
__global__ __launch_bounds__(256) void k_bnB(
        const float* __restrict__ psumT, const float* __restrict__ psqT,
        const float* __restrict__ gamma, const float* __restrict__ beta,
        float* __restrict__ scale, float* __restrict__ shift) {
    const int f = blockIdx.x;
    const int tid = threadIdx.x;
    const float* ps = psumT + (size_t)f * 4096;
    const float* pq = psqT + (size_t)f * 4096;
    float s = 0.0f, q = 0.0f;
    for (int p = tid; p < 4096; p += 256) { s += ps[p]; q += pq[p]; }
    #pragma unroll
    for (int o = 32; o > 0; o >>= 1) {
        s += __shfl_down(s, o, 64);
        q += __shfl_down(q, o, 64);
    }
    __shared__ float rs[4], rq[4];
    const int wv = tid >> 6;
    if ((tid & 63) == 0) { rs[wv] = s; rq[wv] = q; }
    __syncthreads();
    if (tid == 0) {
        float S = rs[0] + rs[1] + rs[2] + rs[3];
        float Q = rq[0] + rq[1] + rq[2] + rq[3];
        float mean = S * (1.0f / NB);
        float var = Q * (1.0f / NB) - mean * mean;
        float sc = gamma[f] * rsqrtf(var + 1e-5f);
        scale[f] = sc;
        shift[f] = beta[f] - mean * sc;
    }
}

// K4: BN-apply + LeakyReLU + concat + FC(162->2) + softmax (f16 flat).
__global__ __launch_bounds__(256) void k_fc(
        const _Float16* __restrict__ flatH, const float* __restrict__ scale,
        const float* __restrict__ shift, const float* __restrict__ ag,
        const float* __restrict__ fcw, const float* __restrict__ fcb,
        float* __restrict__ out) {
    const int lane = threadIdx.x & 63;
    const int b = blockIdx.x * 4 + (threadIdx.x >> 6);
    const _Float16* fr = flatH + (size_t)b * NF;
    float p0 = 0.0f, p1 = 0.0f;
    #pragma unroll
    for (int i = 0; i < 3; ++i) {
        const int f = lane + i * 64;
        if (f < NF) {
            float xn = (float)fr[f] * scale[f] + shift[f];
            float a = xn >= 0.0f ? xn : 0.01f * xn;
            p0 += a * fcw[f];
            p1 += a * fcw[162 + f];
        }
    }
    #pragma unroll
    for (int o = 32; o > 0; o >>= 1) {
        p0 += __shfl_down(p0, o, 64);
        p1 += __shfl_down(p1, o, 64);
    }
    if (lane == 0) {
        float a0 = ag[(size_t)b * 2 + 0], a1 = ag[(size_t)b * 2 + 1];
        float l0 = p0 + a0 * fcw[160] + a1 * fcw[161] + fcb[0];
        float l1 = p1 + a0 * fcw[162 + 160] + a1 * fcw[162 + 161] + fcb[1];
        float m = fmaxf(l0, l1);
        float e0 = __expf(l0 - m), e1 = __expf(l1 - m);
        float inv = 1.0f / (e0 + e1);
        out[(size_t)b * 2 + 0] = e0 * inv;
        out[(size_t)b * 2 + 1] = e1 * inv;
    }
}

extern "C" void kernel_launch(void* const* d_in, const int* in_sizes, int n_in,
                              void* d_out, int out_size, void* d_ws, size_t ws_size,
                              hipStream_t stream) {
    const float* x     = (const float*)d_in[0];
    const float* ag    = (const float*)d_in[1];
    const float* wih0  = (const float*)d_in[2];
    const float* whh0  = (const float*)d_in[3];
    const float* bih0  = (const float*)d_in[4];
    const float* bhh0  = (const float*)d_in[5];
    const float* wih1  = (const float*)d_in[6];
    const float* whh1  = (const float*)d_in[7];
    const float* bih1  = (const float*)d_in[8];
    const float* bhh1  = (const float*)d_in[9];
    const float* gamma = (const float*)d_in[10];
    const float* beta  = (const float*)d_in[11];
    const float* fcw   = (const float*)d_in[12];
    const float* fcb   = (const float*)d_in[13];
    float* out = (float*)d_out;

    float* ws = (float*)d_ws;
    _Float16* xgH   = (_Float16*)ws;               // 10,485,760 halfs (5,242,880 f32-slots)
    _Float16* flatH = (_Float16*)(ws + 5242880);   //  2,621,440 halfs (1,310,720 slots)
    float* psumT = ws + 6553600;                   //    655,360 (160 x 4096)
    float* psqT  = ws + 7208960;                   //    655,360
    float* scale = ws + 7864320;                   //        160
    float* shift = ws + 7864480;                   //        160
    half8* Bf    = (half8*)(ws + 7864640);         //      8,192 f32-slots (32 KB)
    float* bsum  = ws + 7872832;                   //         64

    k_prep<<<dim3(8),    dim3(256), 0, stream>>>(wih0, bih0, bhh0, Bf, bsum);
    k_proj<<<dim3(2560), dim3(256), 0, stream>>>(x, Bf, bsum, xgH);
    k_lstm<<<dim3(4096), dim3(256), 0, stream>>>(xgH, whh0, wih1, whh1, bih1, bhh1,
                                                 flatH, psumT, psqT);
    k_bnB<<<dim3(160),  dim3(256), 0, stream>>>(psumT, psqT, gamma, beta, scale, shift);
    k_fc<<<dim3(4096),  dim3(256), 0, stream>>>(flatH, scale, shift, ag, fcw, fcb, out);
}